// Round 9
// baseline (120.155 us; speedup 1.0000x reference)
//
#include <hip/hip_runtime.h>
#include <math.h>

#define BB 512
#define SS 200
#define DD 512
#define KK 128
#define RR (BB * SS)   // 102400 rows

typedef __attribute__((ext_vector_type(8))) short bf16x8;
typedef __attribute__((ext_vector_type(4))) short bf16x4;
typedef __attribute__((ext_vector_type(4))) float f32x4;

__device__ inline unsigned short f2bf(float f) {
    union { float f; unsigned int u; } v; v.f = f;
    unsigned int r = v.u + 0x7FFFu + ((v.u >> 16) & 1u);   // RNE
    return (unsigned short)(r >> 16);
}

__device__ inline float fast_tanh(float x) {
    x = fminf(10.f, fmaxf(-10.f, x));
    float t = exp2f(x * 2.885390081777927f);          // e^(2x)
    return (t - 1.f) * __builtin_amdgcn_rcpf(t + 1.f);
}

// ---------------------------------------------------------------------------
// Wt2 in MFMA-fragment order: tile t (d=t*32..), col-block n (k=n*16..):
//   Wt2[((t*8+n)*64+l)*8 + j] = bf16(W[d(t,l,j)*KK + k(n,l)])
//   k = n*16 + (l&15),  d = t*32 + (l>>4)*8 + j
// ---------------------------------------------------------------------------
__global__ void wt_kernel(const float* __restrict__ W, unsigned short* __restrict__ Wt2) {
    int i = blockIdx.x * 256 + threadIdx.x;   // over 16*8*64*8 = 65536
    int j = i & 7;
    int l = (i >> 3) & 63;
    int n = (i >> 9) & 7;
    int t = i >> 12;
    int k = n * 16 + (l & 15);
    int d = t * 32 + (l >> 4) * 8 + j;
    Wt2[i] = f2bf(W[d * KK + k]);
}

// ---------------------------------------------------------------------------
// logits[row] = sum_k tanh(tfh[row,:] . W[:,k]) * wpk[k] + bias[row%SS]
// ZERO-BARRIER: each wave stages its own 32 rows into wave-private LDS
// (coalesced 128B-segment loads, fp32->bf16 in-reg), reads its MFMA frags
// back, accumulates. B fragment-ordered straight from L2. Waves free-run.
// 800 blocks x 256 thr (4 waves), 4 blocks/CU.
// ---------------------------------------------------------------------------
__global__ __launch_bounds__(256, 4) void logits_kernel(
    const float* __restrict__ tfh,           // [RR, DD]
    const unsigned short* __restrict__ Wt2,  // fragment-ordered
    const float* __restrict__ wpk,           // [KK]
    const float* __restrict__ bias,          // [SS]
    float* __restrict__ logits)              // [RR]
{
    __shared__ unsigned short As[128][40];   // 4 wave-private 32-row strips

    int tid = threadIdx.x;
    int w   = tid >> 6;        // wave 0..3
    int l   = tid & 63;
    int l15 = l & 15;
    int g   = l >> 4;
    int brow = blockIdx.x * 128;

    // wave-private staging: within wave, f = l + 64*j (j=0..3):
    //   local row = f>>3 (0..31), float4-col = f&7
    // 8 consecutive lanes cover one 128B row segment (coalesced).
    int rl = l >> 3;            // local row base 0..7
    int c4 = l & 7;
    const float* ap = tfh + (size_t)(brow + w * 32 + rl) * DD + c4 * 4;

    const unsigned short* bp = Wt2 + (size_t)l * 8;

    f32x4 acc[2][8];
    #pragma unroll
    for (int m = 0; m < 2; ++m)
        #pragma unroll
        for (int n = 0; n < 8; ++n) acc[m][n] = (f32x4){0.f, 0.f, 0.f, 0.f};

    for (int t = 0; t < 16; ++t) {
        int d0 = t * 32;
        // --- stage this wave's 32 rows x 32 d: issue all 4 loads first ---
        float4 v0 = *(const float4*)(ap + d0);
        float4 v1 = *(const float4*)(ap + d0 + (size_t)8 * DD);
        float4 v2 = *(const float4*)(ap + d0 + (size_t)16 * DD);
        float4 v3 = *(const float4*)(ap + d0 + (size_t)24 * DD);
        bf16x4 p0, p1, p2, p3;
        p0[0] = (short)f2bf(v0.x); p0[1] = (short)f2bf(v0.y);
        p0[2] = (short)f2bf(v0.z); p0[3] = (short)f2bf(v0.w);
        p1[0] = (short)f2bf(v1.x); p1[1] = (short)f2bf(v1.y);
        p1[2] = (short)f2bf(v1.z); p1[3] = (short)f2bf(v1.w);
        p2[0] = (short)f2bf(v2.x); p2[1] = (short)f2bf(v2.y);
        p2[2] = (short)f2bf(v2.z); p2[3] = (short)f2bf(v2.w);
        p3[0] = (short)f2bf(v3.x); p3[1] = (short)f2bf(v3.y);
        p3[2] = (short)f2bf(v3.z); p3[3] = (short)f2bf(v3.w);
        *(bf16x4*)&As[w * 32 + rl     ][c4 * 4] = p0;
        *(bf16x4*)&As[w * 32 + rl +  8][c4 * 4] = p1;
        *(bf16x4*)&As[w * 32 + rl + 16][c4 * 4] = p2;
        *(bf16x4*)&As[w * 32 + rl + 24][c4 * 4] = p3;
        // implicit lgkmcnt wait (same-wave LDS dependency) — no barrier
        bf16x8 af0 = *(const bf16x8*)&As[w * 32 + l15][g * 8];
        bf16x8 af1 = *(const bf16x8*)&As[w * 32 + 16 + l15][g * 8];
        const unsigned short* bt = bp + (size_t)t * (8 * 64 * 8);
        #pragma unroll
        for (int nb = 0; nb < 4; ++nb) {
            bf16x8 b0 = *(const bf16x8*)(bt + (2 * nb) * 512);
            bf16x8 b1 = *(const bf16x8*)(bt + (2 * nb + 1) * 512);
            acc[0][2*nb]   = __builtin_amdgcn_mfma_f32_16x16x32_bf16(af0, b0, acc[0][2*nb],   0, 0, 0);
            acc[1][2*nb]   = __builtin_amdgcn_mfma_f32_16x16x32_bf16(af1, b0, acc[1][2*nb],   0, 0, 0);
            acc[0][2*nb+1] = __builtin_amdgcn_mfma_f32_16x16x32_bf16(af0, b1, acc[0][2*nb+1], 0, 0, 0);
            acc[1][2*nb+1] = __builtin_amdgcn_mfma_f32_16x16x32_bf16(af1, b1, acc[1][2*nb+1], 0, 0, 0);
        }
    }

    // --- epilogue: tanh, weight by wpk, reduce over k within 16-lane group ---
    float wv[8];
    #pragma unroll
    for (int n = 0; n < 8; ++n) wv[n] = wpk[n * 16 + l15];

    float rs[2][4];
    #pragma unroll
    for (int m = 0; m < 2; ++m)
        #pragma unroll
        for (int r = 0; r < 4; ++r) rs[m][r] = 0.f;
    #pragma unroll
    for (int m = 0; m < 2; ++m)
        #pragma unroll
        for (int n = 0; n < 8; ++n)
            #pragma unroll
            for (int r = 0; r < 4; ++r)
                rs[m][r] += fast_tanh(acc[m][n][r]) * wv[n];
    #pragma unroll
    for (int m = 0; m < 2; ++m)
        #pragma unroll
        for (int r = 0; r < 4; ++r) {
            float v = rs[m][r];
            v += __shfl_xor(v, 1, 64);
            v += __shfl_xor(v, 2, 64);
            v += __shfl_xor(v, 4, 64);
            v += __shfl_xor(v, 8, 64);
            rs[m][r] = v;
        }
    if (l15 == 0) {
        #pragma unroll
        for (int m = 0; m < 2; ++m)
            #pragma unroll
            for (int r = 0; r < 4; ++r) {
                int grow = brow + w * 32 + m * 16 + g * 4 + r;
                logits[grow] = rs[m][r] + bias[grow % SS];
            }
    }
}

// ---------------------------------------------------------------------------
// Pt = softmax(logits[b,:]); out[b,s,:] = Pt[s] * tfh[b,s,:]
// tfh re-read hits L3; non-temporal stores keep tfh resident.
// ---------------------------------------------------------------------------
__global__ __launch_bounds__(1024) void softmax_mul_kernel(
    const float* __restrict__ logits,
    const float* __restrict__ tfh,
    float* __restrict__ out)
{
    int b = blockIdx.x;
    int tid = threadIdx.x;
    __shared__ float Pt[SS];
    __shared__ float wpart[16];

    float v = (tid < SS) ? logits[(size_t)b * SS + tid] : -INFINITY;
    float m = v;
    #pragma unroll
    for (int off = 32; off > 0; off >>= 1) m = fmaxf(m, __shfl_xor(m, off, 64));
    if ((tid & 63) == 0) wpart[tid >> 6] = m;
    __syncthreads();
    m = -INFINITY;
    #pragma unroll
    for (int i = 0; i < 16; ++i) m = fmaxf(m, wpart[i]);
    float e = (tid < SS) ? expf(v - m) : 0.f;
    float ssum = e;
    #pragma unroll
    for (int off = 32; off > 0; off >>= 1) ssum += __shfl_xor(ssum, off, 64);
    __syncthreads();
    if ((tid & 63) == 0) wpart[tid >> 6] = ssum;
    __syncthreads();
    ssum = 0.f;
    #pragma unroll
    for (int i = 0; i < 16; ++i) ssum += wpart[i];
    if (tid < SS) Pt[tid] = e / ssum;
    __syncthreads();

    const f32x4* src = (const f32x4*)(tfh + (size_t)b * SS * DD);
    f32x4*       dst = (f32x4*)(out + (size_t)b * SS * DD);
    const int n4 = SS * DD / 4;   // 25600; 128 f32x4 per s-row
    for (int i = tid; i < n4; i += 1024) {
        float p = Pt[i >> 7];
        f32x4 x = src[i];
        x = x * p;
        __builtin_nontemporal_store(x, dst + i);
    }
}

// ---------------------------------------------------------------------------
extern "C" void kernel_launch(void* const* d_in, const int* in_sizes, int n_in,
                              void* d_out, int out_size, void* d_ws, size_t ws_size,
                              hipStream_t stream) {
    const float* tfh   = (const float*)d_in[1];
    const float* wVt1  = (const float*)d_in[7];
    const float* wp1   = (const float*)d_in[8];
    const float* bias1 = (const float*)d_in[9];
    float* out = (float*)d_out;

    // ws: Wt2 bf16 fragment-ordered (128KB) | logits f32 [RR] (400KB)
    unsigned short* Wt2 = (unsigned short*)d_ws;
    float* logits = (float*)((char*)d_ws + 16 * 8 * 64 * 8 * sizeof(unsigned short));

    wt_kernel<<<(16 * 8 * 64 * 8) / 256, 256, 0, stream>>>(wVt1, Wt2);
    logits_kernel<<<RR / 128, 256, 0, stream>>>(tfh, Wt2, wp1 + KK, bias1, logits);
    softmax_mul_kernel<<<BB, 1024, 0, stream>>>(logits, tfh, out);
}